// Round 10
// baseline (92.024 us; speedup 1.0000x reference)
//
#include <hip/hip_runtime.h>

typedef __attribute__((ext_vector_type(8))) short s8v;
typedef __attribute__((ext_vector_type(4))) short s4v;
typedef __attribute__((ext_vector_type(4))) float fx4;
typedef unsigned short u16;
typedef unsigned int u32;
typedef unsigned char u8;

#define QK_SCALE 0.1803368801111204f  /* 0.125 * log2(e) */

#if __has_builtin(__builtin_amdgcn_exp2f)
#define EXP2(x) __builtin_amdgcn_exp2f(x)
#else
#define EXP2(x) exp2f(x)
#endif

static __device__ __forceinline__ u16 f2bf(float f) {
    u32 u = __float_as_uint(f);
    u += 0x7fffu + ((u >> 16) & 1u);
    return (u16)(u >> 16);
}
static __device__ __forceinline__ float bf2f(u16 h) {
    return __uint_as_float(((u32)h) << 16);
}
// truncate-pack two f32 -> two bf16 in one v_perm (softmax cancels the common bias)
static __device__ __forceinline__ int packtrunc(float a, float b) {
    return (int)__builtin_amdgcn_perm(__float_as_uint(b), __float_as_uint(a), 0x07060302u);
}
// VALU-only exp2: n=rndne(x), deg-4 Taylor of e^u on u=(x-n)ln2 in [-.347,.347]
// (rel err ~6e-5 << bf16-P truncation 3.9e-3), exponent added via integer trick.
static __device__ __forceinline__ float poly_exp2(float x) {
    const float n = rintf(x);
    const float u = (x - n) * 0.69314718056f;
    float p = fmaf(u, 0.0416666679f, 0.1666666667f);
    p = fmaf(u, p, 0.5f);
    p = fmaf(u, p, 1.0f);
    p = fmaf(u, p, 1.0f);
    const int i = (int)n;
    return __uint_as_float(__float_as_uint(p) + (((u32)i) << 23));
}

static __device__ __forceinline__ fx4 mfma16(s4v a, s4v b, fx4 c) {
#if __has_builtin(__builtin_amdgcn_mfma_f32_16x16x16bf16_1k)
    return __builtin_amdgcn_mfma_f32_16x16x16bf16_1k(a, b, c, 0, 0, 0);
#else
    asm("v_mfma_f32_16x16x16_bf16 %0, %1, %2, %3" : "=v"(c) : "v"(a), "v"(b), "v"(c));
    return c;
#endif
}

// ---------------- K1: qkv proj -> Qh (scaled hi/lo), Kh (hi/lo), Vt (transposed bf16) ----------------
// Also initializes the static V^T rows (d=8 ones, d=9..15 zeros) for Vt0 AND Vt1.
__global__ __launch_bounds__(192) void qkv_proj_kernel(
    const float* __restrict__ X, const float* __restrict__ W,
    const float* __restrict__ bias,
    u16* __restrict__ Qh, u16* __restrict__ Kh, u16* __restrict__ Vt,
    u32* __restrict__ VtBoth)
{
    {
        const int gt = blockIdx.x * 192 + threadIdx.x;
        #pragma unroll
        for (int i = 0; i < 3; ++i) {
            const int idx = gt + i * 196608;
            if (idx < 524288) {
                const int region = idx >> 6, word = idx & 63;
                VtBoth[region * 128 + 64 + word] = (word < 8) ? 0x3f803f80u : 0u;
            }
        }
    }
    __shared__ __align__(16) float xsT[64 * 12];
    const int row0 = blockIdx.x * 8;
    const int t = threadIdx.x;
    if (t < 64) {
        #pragma unroll
        for (int r = 0; r < 8; ++r)
            xsT[t * 12 + r] = X[(size_t)(row0 + r) * 64 + t];
    }
    __syncthreads();
    const int j = t;
    const float bj = bias[j];
    float acc[8];
    #pragma unroll
    for (int r = 0; r < 8; ++r) acc[r] = bj;
    #pragma unroll 4
    for (int k = 0; k < 64; ++k) {
        const float w = W[k * 192 + j];
        const float4 x0 = *(const float4*)&xsT[k * 12];
        const float4 x1 = *(const float4*)&xsT[k * 12 + 4];
        acc[0] = fmaf(x0.x, w, acc[0]);
        acc[1] = fmaf(x0.y, w, acc[1]);
        acc[2] = fmaf(x0.z, w, acc[2]);
        acc[3] = fmaf(x0.w, w, acc[3]);
        acc[4] = fmaf(x1.x, w, acc[4]);
        acc[5] = fmaf(x1.y, w, acc[5]);
        acc[6] = fmaf(x1.z, w, acc[6]);
        acc[7] = fmaf(x1.w, w, acc[7]);
    }
    const int c = j & 63;
    const int h = c >> 3, d = c & 7;
    #pragma unroll
    for (int r = 0; r < 8; ++r) {
        const int R = row0 + r;
        const int bi = R >> 11, i = R & 2047;
        const int bh = bi * 8 + h;
        const float v = acc[r];
        if (j < 64) {
            const float qs = v * QK_SCALE;
            const u16 hh = f2bf(qs);
            const u16 ll = f2bf(qs - bf2f(hh));
            u16* qp = Qh + ((size_t)(bh * 2048 + i)) * 16 + d;
            qp[0] = hh; qp[8] = ll;
        } else if (j < 128) {
            const u16 hh = f2bf(v);
            const u16 ll = f2bf(v - bf2f(hh));
            u16* kp = Kh + ((size_t)(bh * 128 + (i >> 4)) * 16 + (i & 15)) * 16 + d;
            kp[0] = hh; kp[8] = ll;
        } else {
            Vt[((size_t)(bh * 128 + (i >> 4)) * 16 + d) * 16 + (i & 15)] = f2bf(v);
        }
    }
}

// ---------------- MFMA attention v7: v6 structure + TRANS/VALU exp split ----------------
// grid (bh=32, qt=16, sp=2) = 1024 blocks = 4 blocks/CU. Block: 128 q x 1024 keys.
// Wave w: keys [w*256,(w+1)*256) for all 128 q (8 qg chains), 2-seg register prefetch.
// QK: mfma_16x16x32: A lane(key=l&15,g=l>>4) = K hi(g even)/lo(g odd); B=Q[qhi,qhi,qlo,qlo].
// C: col=q=l&15, row=key=4g+r. P=exp2(S): scores 0,2 on TRANS pipe (v_exp_f32),
// scores 1,3 on VALU pipe (poly_exp2) -> both pipes run concurrently (exp-split A/B).
// packtrunc = B-frag of 16x16x16 (k=4g+j). A_V rows: d=0..7 V^T, 8=ones (denominator).
// Cross-wave key reduce via 32KB LDS.
__global__ __launch_bounds__(256, 4) void attn_mfma7_kernel(
    const u16* __restrict__ Qh, const u8* __restrict__ Khb,
    const u8* __restrict__ Vtb, float* __restrict__ Part)
{
    __shared__ __align__(16) float Lr[4][8][64][4];   // [wave][qg][lane][4] = 32KB
    const int bh = blockIdx.x, qt = blockIdx.y, sp = blockIdx.z;
    const int tid = threadIdx.x, w = tid >> 6, l = tid & 63;
    const int g = l >> 4, ql = l & 15;

    s8v bq[8];
    #pragma unroll
    for (int qg = 0; qg < 8; ++qg)
        bq[qg] = *(const s8v*)(Qh + ((size_t)(bh * 2048 + qt * 128 + qg * 16 + ql)) * 16
                               + (g >> 1) * 8);

    const size_t kvoff = (size_t)bh * 65536 + sp * 32768 + w * 8192;
    const u8* kptr = Khb + kvoff + ql * 32 + (g & 1) * 16;
    const u8* vptr = Vtb + kvoff + ql * 32 + g * 8;

    fx4 acc[8];
    #pragma unroll
    for (int qg = 0; qg < 8; ++qg) acc[qg] = fx4{0.f, 0.f, 0.f, 0.f};
    const fx4 zf = {0.f, 0.f, 0.f, 0.f};

    s8v k0 = *(const s8v*)(kptr);
    s8v k1 = *(const s8v*)(kptr + 512);
    s4v v0 = *(const s4v*)(vptr);
    s4v v1 = *(const s4v*)(vptr + 512);

#define QK_COMPUTE(KA, VA)                                                      \
    {                                                                           \
        _Pragma("unroll")                                                       \
        for (int qg = 0; qg < 8; ++qg) {                                        \
            fx4 s = __builtin_amdgcn_mfma_f32_16x16x32_bf16(KA, bq[qg], zf, 0, 0, 0); \
            const float e0 = EXP2(s[0]);                                        \
            const float e1 = poly_exp2(s[1]);                                   \
            const float e2 = EXP2(s[2]);                                        \
            const float e3 = poly_exp2(s[3]);                                   \
            union { int i[2]; s4v v; } bp;                                      \
            bp.i[0] = packtrunc(e0, e1);                                        \
            bp.i[1] = packtrunc(e2, e3);                                        \
            acc[qg] = mfma16(VA, bp.v, acc[qg]);                                \
        }                                                                       \
    }

    #pragma unroll 1
    for (int seg = 0; seg < 16; seg += 2) {
        const s8v k2 = *(const s8v*)(kptr + (seg + 2) * 512);
        const s4v v2 = *(const s4v*)(vptr + (seg + 2) * 512);
        const s8v k3 = *(const s8v*)(kptr + (seg + 3) * 512);
        const s4v v3 = *(const s4v*)(vptr + (seg + 3) * 512);
        QK_COMPUTE(k0, v0);
        QK_COMPUTE(k1, v1);
        k0 = k2; v0 = v2; k1 = k3; v1 = v3;
    }
#undef QK_COMPUTE

    // cross-wave reduction over key-quarters
    #pragma unroll
    for (int qg = 0; qg < 8; ++qg)
        *(fx4*)&Lr[w][qg][l][0] = acc[qg];
    __syncthreads();

    #pragma unroll
    for (int qq = 0; qq < 2; ++qq) {
        const int qg = w * 2 + qq;
        fx4 fin = {0.f, 0.f, 0.f, 0.f};
        #pragma unroll
        for (int wp = 0; wp < 4; ++wp) {
            const fx4 v = *(const fx4*)&Lr[wp][qg][l][0];
            fin[0] += v[0]; fin[1] += v[1]; fin[2] += v[2]; fin[3] += v[3];
        }
        const int qglob = qt * 128 + qg * 16 + ql;
        float* pp = Part + ((size_t)(bh * 2048 + qglob)) * 24 + sp * 12;
        if (g < 2) {
            const float4 o = {fin[0], fin[1], fin[2], fin[3]};
            *(float4*)(pp + g * 4) = o;
        } else if (g == 2) {
            pp[8] = fin[0];
        }
    }
}

// ---------------- combine split partials ----------------
__global__ __launch_bounds__(256) void attn_combine2_kernel(
    const float* __restrict__ Part, float* __restrict__ M)
{
    const int idx = blockIdx.x * 256 + threadIdx.x;   // 65536 = bh*2048 + q
    const float* pp = Part + (size_t)idx * 24;
    const float inv = 1.0f / (pp[8] + pp[20]);
    float o[8];
    #pragma unroll
    for (int d = 0; d < 8; ++d) o[d] = (pp[d] + pp[12 + d]) * inv;
    const int bh = idx >> 11, q = idx & 2047;
    const int b = bh >> 3, h = bh & 7;
    float* op = M + ((size_t)(b * 2048 + q)) * 64 + h * 8;
    const float4 o0 = {o[0], o[1], o[2], o[3]};
    const float4 o1 = {o[4], o[5], o[6], o[7]};
    *(float4*)op = o0;
    *(float4*)(op + 4) = o1;
}

// ---------------- proj64: mode 0 -> stage-2 Qh/Kh/Vt buffers; mode 1 -> plain f32 out ----------------
// q1 reshape: p-row rr, col c -> bh=bi*8+(rr>>8), key=(rr&255)*8+(c>>3), d=c&7
__global__ __launch_bounds__(64) void proj64_kernel(
    const float* __restrict__ X, const float* __restrict__ W,
    const float* __restrict__ bias,
    u16* __restrict__ Qh, u16* __restrict__ Kh, u16* __restrict__ Vt,
    float* __restrict__ Out, int mode)
{
    __shared__ __align__(16) float xsT[64 * 12];
    const int row0 = blockIdx.x * 8;
    const int c = threadIdx.x;
    #pragma unroll
    for (int r = 0; r < 8; ++r)
        xsT[c * 12 + r] = X[(size_t)(row0 + r) * 64 + c];
    __syncthreads();
    const float bc = bias[c];
    float acc[8];
    #pragma unroll
    for (int r = 0; r < 8; ++r) acc[r] = bc;
    #pragma unroll 4
    for (int k = 0; k < 64; ++k) {
        const float w = W[k * 64 + c];
        const float4 x0 = *(const float4*)&xsT[k * 12];
        const float4 x1 = *(const float4*)&xsT[k * 12 + 4];
        acc[0] = fmaf(x0.x, w, acc[0]);
        acc[1] = fmaf(x0.y, w, acc[1]);
        acc[2] = fmaf(x0.z, w, acc[2]);
        acc[3] = fmaf(x0.w, w, acc[3]);
        acc[4] = fmaf(x1.x, w, acc[4]);
        acc[5] = fmaf(x1.y, w, acc[5]);
        acc[6] = fmaf(x1.z, w, acc[6]);
        acc[7] = fmaf(x1.w, w, acc[7]);
    }
    if (mode == 0) {
        #pragma unroll
        for (int r = 0; r < 8; ++r) {
            const int R = row0 + r;
            const int bi = R >> 11, rr = R & 2047;
            const int bh = bi * 8 + (rr >> 8);
            const int key = (rr & 255) * 8 + (c >> 3);
            const int d = c & 7;
            const int kg = key >> 4, kr = key & 15;
            const float p = acc[r];
            const float qs = p * QK_SCALE;
            const u16 qh = f2bf(qs);
            const u16 qlo = f2bf(qs - bf2f(qh));
            const u16 kh = f2bf(p);
            const u16 kl = f2bf(p - bf2f(kh));
            u16* qp = Qh + ((size_t)(bh * 2048 + key)) * 16 + d;
            qp[0] = qh; qp[8] = qlo;
            u16* kp = Kh + ((size_t)(bh * 128 + kg) * 16 + kr) * 16 + d;
            kp[0] = kh; kp[8] = kl;
            Vt[((size_t)(bh * 128 + kg) * 16 + d) * 16 + kr] = f2bf(p);
        }
    } else {
        #pragma unroll
        for (int r = 0; r < 8; ++r)
            Out[(size_t)(row0 + r) * 64 + c] = acc[r];
    }
}

extern "C" void kernel_launch(void* const* d_in, const int* in_sizes, int n_in,
                              void* d_out, int out_size, void* d_ws, size_t ws_size,
                              hipStream_t stream) {
    const float* x    = (const float*)d_in[0];
    const float* Wqkv = (const float*)d_in[1];
    const float* bqkv = (const float*)d_in[2];
    const float* W1   = (const float*)d_in[3];
    const float* b1   = (const float*)d_in[4];
    float* out = (float*)d_out;
    u8* w8 = (u8*)d_ws;

    // byte layout (20 MiB total)
    u16*   Qh0  = (u16*)(w8);                       // 2 MiB
    u16*   Kh0  = (u16*)(w8 + (2u << 20));          // 2 MiB
    u16*   Vt0  = (u16*)(w8 + (4u << 20));          // 2 MiB
    u16*   Vt1  = (u16*)(w8 + (6u << 20));          // 2 MiB (adjacent to Vt0 for init)
    u16*   Qh1  = (u16*)(w8 + (8u << 20));          // 2 MiB
    u16*   Kh1  = (u16*)(w8 + (10u << 20));         // 2 MiB
    float* Part = (float*)(w8 + (12u << 20));       // 6 MiB
    float* M1   = (float*)(w8 + (18u << 20));       // 2 MiB
    float* M2   = (float*)(w8);                     // overlays Qh0 (dead by then)

    qkv_proj_kernel<<<1024, 192, 0, stream>>>(x, Wqkv, bqkv, Qh0, Kh0, Vt0, (u32*)Vt0);
    attn_mfma7_kernel<<<dim3(32, 16, 2), 256, 0, stream>>>(Qh0, (const u8*)Kh0, (const u8*)Vt0, Part);
    attn_combine2_kernel<<<256, 256, 0, stream>>>(Part, M1);
    proj64_kernel<<<1024, 64, 0, stream>>>(M1, W1, b1, Qh1, Kh1, Vt1, nullptr, 0);
    attn_mfma7_kernel<<<dim3(32, 16, 2), 256, 0, stream>>>(Qh1, (const u8*)Kh1, (const u8*)Vt1, Part);
    attn_combine2_kernel<<<256, 256, 0, stream>>>(Part, M2);
    proj64_kernel<<<1024, 64, 0, stream>>>(M2, W1, b1, nullptr, nullptr, nullptr, out, 1);
}

// Round 11
// 73.153 us; speedup vs baseline: 1.2580x; 1.2580x over previous
//
#include <hip/hip_runtime.h>

typedef __attribute__((ext_vector_type(8))) short s8v;
typedef __attribute__((ext_vector_type(4))) short s4v;
typedef __attribute__((ext_vector_type(4))) float fx4;
typedef unsigned short u16;
typedef unsigned int u32;
typedef unsigned char u8;

#define QK_SCALE 0.1803368801111204f  /* 0.125 * log2(e) */

#if __has_builtin(__builtin_amdgcn_exp2f)
#define EXP2(x) __builtin_amdgcn_exp2f(x)
#else
#define EXP2(x) exp2f(x)
#endif

static __device__ __forceinline__ u16 f2bf(float f) {
    u32 u = __float_as_uint(f);
    u += 0x7fffu + ((u >> 16) & 1u);
    return (u16)(u >> 16);
}
static __device__ __forceinline__ float bf2f(u16 h) {
    return __uint_as_float(((u32)h) << 16);
}
// truncate-pack two f32 -> two bf16 in one v_perm (softmax cancels the common bias)
static __device__ __forceinline__ int packtrunc(float a, float b) {
    return (int)__builtin_amdgcn_perm(__float_as_uint(b), __float_as_uint(a), 0x07060302u);
}

static __device__ __forceinline__ fx4 mfma16(s4v a, s4v b, fx4 c) {
#if __has_builtin(__builtin_amdgcn_mfma_f32_16x16x16bf16_1k)
    return __builtin_amdgcn_mfma_f32_16x16x16bf16_1k(a, b, c, 0, 0, 0);
#else
    asm("v_mfma_f32_16x16x16_bf16 %0, %1, %2, %3" : "=v"(c) : "v"(a), "v"(b), "v"(c));
    return c;
#endif
}

// ---------------- K1: qkv proj -> Qh (scaled hi/lo), Kh (hi/lo), Vt (transposed bf16) ----------------
// Also initializes the static V^T rows (d=8 ones, d=9..15 zeros) for Vt0 AND Vt1.
__global__ __launch_bounds__(192) void qkv_proj_kernel(
    const float* __restrict__ X, const float* __restrict__ W,
    const float* __restrict__ bias,
    u16* __restrict__ Qh, u16* __restrict__ Kh, u16* __restrict__ Vt,
    u32* __restrict__ VtBoth)
{
    {
        const int gt = blockIdx.x * 192 + threadIdx.x;
        #pragma unroll
        for (int i = 0; i < 3; ++i) {
            const int idx = gt + i * 196608;
            if (idx < 524288) {
                const int region = idx >> 6, word = idx & 63;
                VtBoth[region * 128 + 64 + word] = (word < 8) ? 0x3f803f80u : 0u;
            }
        }
    }
    __shared__ __align__(16) float xsT[64 * 12];
    const int row0 = blockIdx.x * 8;
    const int t = threadIdx.x;
    if (t < 64) {
        #pragma unroll
        for (int r = 0; r < 8; ++r)
            xsT[t * 12 + r] = X[(size_t)(row0 + r) * 64 + t];
    }
    __syncthreads();
    const int j = t;
    const float bj = bias[j];
    float acc[8];
    #pragma unroll
    for (int r = 0; r < 8; ++r) acc[r] = bj;
    #pragma unroll 4
    for (int k = 0; k < 64; ++k) {
        const float w = W[k * 192 + j];
        const float4 x0 = *(const float4*)&xsT[k * 12];
        const float4 x1 = *(const float4*)&xsT[k * 12 + 4];
        acc[0] = fmaf(x0.x, w, acc[0]);
        acc[1] = fmaf(x0.y, w, acc[1]);
        acc[2] = fmaf(x0.z, w, acc[2]);
        acc[3] = fmaf(x0.w, w, acc[3]);
        acc[4] = fmaf(x1.x, w, acc[4]);
        acc[5] = fmaf(x1.y, w, acc[5]);
        acc[6] = fmaf(x1.z, w, acc[6]);
        acc[7] = fmaf(x1.w, w, acc[7]);
    }
    const int c = j & 63;
    const int h = c >> 3, d = c & 7;
    #pragma unroll
    for (int r = 0; r < 8; ++r) {
        const int R = row0 + r;
        const int bi = R >> 11, i = R & 2047;
        const int bh = bi * 8 + h;
        const float v = acc[r];
        if (j < 64) {
            const float qs = v * QK_SCALE;
            const u16 hh = f2bf(qs);
            const u16 ll = f2bf(qs - bf2f(hh));
            u16* qp = Qh + ((size_t)(bh * 2048 + i)) * 16 + d;
            qp[0] = hh; qp[8] = ll;
        } else if (j < 128) {
            const u16 hh = f2bf(v);
            const u16 ll = f2bf(v - bf2f(hh));
            u16* kp = Kh + ((size_t)(bh * 128 + (i >> 4)) * 16 + (i & 15)) * 16 + d;
            kp[0] = hh; kp[8] = ll;
        } else {
            Vt[((size_t)(bh * 128 + (i >> 4)) * 16 + d) * 16 + (i & 15)] = f2bf(v);
        }
    }
}

// ---------------- MFMA attention v8: R9 structure + explicit 3-phase ILP pipeline ----------------
// grid (bh=32, qt=16, sp=2) = 1024 blocks = 4 blocks/CU. Block: 128 q x 1024 keys.
// Wave w: keys [w*256,(w+1)*256) for all 128 q (8 qg chains), 2-seg register prefetch.
// Per seg-half, qg batch of 4: phase1 = 4 independent QK MFMAs back-to-back (issue
// covers MFMA latency), phase2 = 16 exps + 8 perms (independent), phase3 = 4 PV MFMAs.
// No in-order-issue stall windows (R10 evidence: chains were the limiter).
// QK: mfma_16x16x32: A lane(key=l&15,g=l>>4) = K hi(g even)/lo(g odd); B=Q[qhi,qhi,qlo,qlo].
// C: col=q=l&15, row=key=4g+r. P=exp2(S) -> packtrunc = B-frag of 16x16x16 (k=4g+j).
// A_V rows: d=0..7 V^T, 8=ones (denominator). Cross-wave key reduce via 32KB LDS.
__global__ __launch_bounds__(256, 4) void attn_mfma8_kernel(
    const u16* __restrict__ Qh, const u8* __restrict__ Khb,
    const u8* __restrict__ Vtb, float* __restrict__ Part)
{
    __shared__ __align__(16) float Lr[4][8][64][4];   // [wave][qg][lane][4] = 32KB
    const int bh = blockIdx.x, qt = blockIdx.y, sp = blockIdx.z;
    const int tid = threadIdx.x, w = tid >> 6, l = tid & 63;
    const int g = l >> 4, ql = l & 15;

    s8v bq[8];
    #pragma unroll
    for (int qg = 0; qg < 8; ++qg)
        bq[qg] = *(const s8v*)(Qh + ((size_t)(bh * 2048 + qt * 128 + qg * 16 + ql)) * 16
                               + (g >> 1) * 8);

    const size_t kvoff = (size_t)bh * 65536 + sp * 32768 + w * 8192;
    const u8* kptr = Khb + kvoff + ql * 32 + (g & 1) * 16;
    const u8* vptr = Vtb + kvoff + ql * 32 + g * 8;

    fx4 acc[8];
    #pragma unroll
    for (int qg = 0; qg < 8; ++qg) acc[qg] = fx4{0.f, 0.f, 0.f, 0.f};
    const fx4 zf = {0.f, 0.f, 0.f, 0.f};

    s8v k0 = *(const s8v*)(kptr);
    s8v k1 = *(const s8v*)(kptr + 512);
    s4v v0 = *(const s4v*)(vptr);
    s4v v1 = *(const s4v*)(vptr + 512);

#define PROCESS(KA, VA)                                                         \
    {                                                                           \
        _Pragma("unroll")                                                       \
        for (int qh = 0; qh < 2; ++qh) {                                        \
            fx4 sv[4];                                                          \
            _Pragma("unroll")                                                   \
            for (int i = 0; i < 4; ++i)                                         \
                sv[i] = __builtin_amdgcn_mfma_f32_16x16x32_bf16(KA, bq[qh * 4 + i], zf, 0, 0, 0); \
            _Pragma("unroll")                                                   \
            for (int i = 0; i < 4; ++i) {                                       \
                union { int i2[2]; s4v v; } bp;                                 \
                bp.i2[0] = packtrunc(EXP2(sv[i][0]), EXP2(sv[i][1]));           \
                bp.i2[1] = packtrunc(EXP2(sv[i][2]), EXP2(sv[i][3]));           \
                acc[qh * 4 + i] = mfma16(VA, bp.v, acc[qh * 4 + i]);            \
            }                                                                   \
        }                                                                       \
    }

    #pragma unroll 1
    for (int seg = 0; seg < 16; seg += 2) {
        const s8v k2 = *(const s8v*)(kptr + (seg + 2) * 512);
        const s4v v2 = *(const s4v*)(vptr + (seg + 2) * 512);
        const s8v k3 = *(const s8v*)(kptr + (seg + 3) * 512);
        const s4v v3 = *(const s4v*)(vptr + (seg + 3) * 512);
        PROCESS(k0, v0);
        PROCESS(k1, v1);
        k0 = k2; v0 = v2; k1 = k3; v1 = v3;
    }
#undef PROCESS

    // cross-wave reduction over key-quarters
    #pragma unroll
    for (int qg = 0; qg < 8; ++qg)
        *(fx4*)&Lr[w][qg][l][0] = acc[qg];
    __syncthreads();

    #pragma unroll
    for (int qq = 0; qq < 2; ++qq) {
        const int qg = w * 2 + qq;
        fx4 fin = {0.f, 0.f, 0.f, 0.f};
        #pragma unroll
        for (int wp = 0; wp < 4; ++wp) {
            const fx4 v = *(const fx4*)&Lr[wp][qg][l][0];
            fin[0] += v[0]; fin[1] += v[1]; fin[2] += v[2]; fin[3] += v[3];
        }
        const int qglob = qt * 128 + qg * 16 + ql;
        float* pp = Part + ((size_t)(bh * 2048 + qglob)) * 24 + sp * 12;
        if (g < 2) {
            const float4 o = {fin[0], fin[1], fin[2], fin[3]};
            *(float4*)(pp + g * 4) = o;
        } else if (g == 2) {
            pp[8] = fin[0];
        }
    }
}

// ---------------- combine split partials ----------------
__global__ __launch_bounds__(256) void attn_combine2_kernel(
    const float* __restrict__ Part, float* __restrict__ M)
{
    const int idx = blockIdx.x * 256 + threadIdx.x;   // 65536 = bh*2048 + q
    const float* pp = Part + (size_t)idx * 24;
    const float inv = 1.0f / (pp[8] + pp[20]);
    float o[8];
    #pragma unroll
    for (int d = 0; d < 8; ++d) o[d] = (pp[d] + pp[12 + d]) * inv;
    const int bh = idx >> 11, q = idx & 2047;
    const int b = bh >> 3, h = bh & 7;
    float* op = M + ((size_t)(b * 2048 + q)) * 64 + h * 8;
    const float4 o0 = {o[0], o[1], o[2], o[3]};
    const float4 o1 = {o[4], o[5], o[6], o[7]};
    *(float4*)op = o0;
    *(float4*)(op + 4) = o1;
}

// ---------------- proj64: mode 0 -> stage-2 Qh/Kh/Vt buffers; mode 1 -> plain f32 out ----------------
// q1 reshape: p-row rr, col c -> bh=bi*8+(rr>>8), key=(rr&255)*8+(c>>3), d=c&7
__global__ __launch_bounds__(64) void proj64_kernel(
    const float* __restrict__ X, const float* __restrict__ W,
    const float* __restrict__ bias,
    u16* __restrict__ Qh, u16* __restrict__ Kh, u16* __restrict__ Vt,
    float* __restrict__ Out, int mode)
{
    __shared__ __align__(16) float xsT[64 * 12];
    const int row0 = blockIdx.x * 8;
    const int c = threadIdx.x;
    #pragma unroll
    for (int r = 0; r < 8; ++r)
        xsT[c * 12 + r] = X[(size_t)(row0 + r) * 64 + c];
    __syncthreads();
    const float bc = bias[c];
    float acc[8];
    #pragma unroll
    for (int r = 0; r < 8; ++r) acc[r] = bc;
    #pragma unroll 4
    for (int k = 0; k < 64; ++k) {
        const float w = W[k * 64 + c];
        const float4 x0 = *(const float4*)&xsT[k * 12];
        const float4 x1 = *(const float4*)&xsT[k * 12 + 4];
        acc[0] = fmaf(x0.x, w, acc[0]);
        acc[1] = fmaf(x0.y, w, acc[1]);
        acc[2] = fmaf(x0.z, w, acc[2]);
        acc[3] = fmaf(x0.w, w, acc[3]);
        acc[4] = fmaf(x1.x, w, acc[4]);
        acc[5] = fmaf(x1.y, w, acc[5]);
        acc[6] = fmaf(x1.z, w, acc[6]);
        acc[7] = fmaf(x1.w, w, acc[7]);
    }
    if (mode == 0) {
        #pragma unroll
        for (int r = 0; r < 8; ++r) {
            const int R = row0 + r;
            const int bi = R >> 11, rr = R & 2047;
            const int bh = bi * 8 + (rr >> 8);
            const int key = (rr & 255) * 8 + (c >> 3);
            const int d = c & 7;
            const int kg = key >> 4, kr = key & 15;
            const float p = acc[r];
            const float qs = p * QK_SCALE;
            const u16 qh = f2bf(qs);
            const u16 qlo = f2bf(qs - bf2f(qh));
            const u16 kh = f2bf(p);
            const u16 kl = f2bf(p - bf2f(kh));
            u16* qp = Qh + ((size_t)(bh * 2048 + key)) * 16 + d;
            qp[0] = qh; qp[8] = qlo;
            u16* kp = Kh + ((size_t)(bh * 128 + kg) * 16 + kr) * 16 + d;
            kp[0] = kh; kp[8] = kl;
            Vt[((size_t)(bh * 128 + kg) * 16 + d) * 16 + kr] = f2bf(p);
        }
    } else {
        #pragma unroll
        for (int r = 0; r < 8; ++r)
            Out[(size_t)(row0 + r) * 64 + c] = acc[r];
    }
}

extern "C" void kernel_launch(void* const* d_in, const int* in_sizes, int n_in,
                              void* d_out, int out_size, void* d_ws, size_t ws_size,
                              hipStream_t stream) {
    const float* x    = (const float*)d_in[0];
    const float* Wqkv = (const float*)d_in[1];
    const float* bqkv = (const float*)d_in[2];
    const float* W1   = (const float*)d_in[3];
    const float* b1   = (const float*)d_in[4];
    float* out = (float*)d_out;
    u8* w8 = (u8*)d_ws;

    // byte layout (20 MiB total)
    u16*   Qh0  = (u16*)(w8);                       // 2 MiB
    u16*   Kh0  = (u16*)(w8 + (2u << 20));          // 2 MiB
    u16*   Vt0  = (u16*)(w8 + (4u << 20));          // 2 MiB
    u16*   Vt1  = (u16*)(w8 + (6u << 20));          // 2 MiB (adjacent to Vt0 for init)
    u16*   Qh1  = (u16*)(w8 + (8u << 20));          // 2 MiB
    u16*   Kh1  = (u16*)(w8 + (10u << 20));         // 2 MiB
    float* Part = (float*)(w8 + (12u << 20));       // 6 MiB
    float* M1   = (float*)(w8 + (18u << 20));       // 2 MiB
    float* M2   = (float*)(w8);                     // overlays Qh0 (dead by then)

    qkv_proj_kernel<<<1024, 192, 0, stream>>>(x, Wqkv, bqkv, Qh0, Kh0, Vt0, (u32*)Vt0);
    attn_mfma8_kernel<<<dim3(32, 16, 2), 256, 0, stream>>>(Qh0, (const u8*)Kh0, (const u8*)Vt0, Part);
    attn_combine2_kernel<<<256, 256, 0, stream>>>(Part, M1);
    proj64_kernel<<<1024, 64, 0, stream>>>(M1, W1, b1, Qh1, Kh1, Vt1, nullptr, 0);
    attn_mfma8_kernel<<<dim3(32, 16, 2), 256, 0, stream>>>(Qh1, (const u8*)Kh1, (const u8*)Vt1, Part);
    attn_combine2_kernel<<<256, 256, 0, stream>>>(Part, M2);
    proj64_kernel<<<1024, 64, 0, stream>>>(M2, W1, b1, nullptr, nullptr, nullptr, out, 1);
}

// Round 12
// 64.199 us; speedup vs baseline: 1.4334x; 1.1395x over previous
//
#include <hip/hip_runtime.h>

typedef __attribute__((ext_vector_type(8))) short s8v;
typedef __attribute__((ext_vector_type(4))) short s4v;
typedef __attribute__((ext_vector_type(4))) float fx4;
typedef unsigned short u16;
typedef unsigned int u32;
typedef unsigned char u8;

#define QK_SCALE 0.1803368801111204f  /* 0.125 * log2(e) */

#if __has_builtin(__builtin_amdgcn_exp2f)
#define EXP2(x) __builtin_amdgcn_exp2f(x)
#else
#define EXP2(x) exp2f(x)
#endif

static __device__ __forceinline__ u16 f2bf(float f) {
    u32 u = __float_as_uint(f);
    u += 0x7fffu + ((u >> 16) & 1u);
    return (u16)(u >> 16);
}
static __device__ __forceinline__ float bf2f(u16 h) {
    return __uint_as_float(((u32)h) << 16);
}
// truncate-pack two f32 -> two bf16 in one v_perm (softmax cancels the common bias)
static __device__ __forceinline__ int packtrunc(float a, float b) {
    return (int)__builtin_amdgcn_perm(__float_as_uint(b), __float_as_uint(a), 0x07060302u);
}

static __device__ __forceinline__ fx4 mfma16(s4v a, s4v b, fx4 c) {
#if __has_builtin(__builtin_amdgcn_mfma_f32_16x16x16bf16_1k)
    return __builtin_amdgcn_mfma_f32_16x16x16bf16_1k(a, b, c, 0, 0, 0);
#elif __has_builtin(__builtin_amdgcn_mfma_f32_16x16x16_bf16)
    return __builtin_amdgcn_mfma_f32_16x16x16_bf16(a, b, c, 0, 0, 0);
#else
    asm("v_mfma_f32_16x16x16_bf16 %0, %1, %2, %3" : "=v"(c) : "v"(a), "v"(b), "v"(c));
    return c;
#endif
}

// ---------------- K1: qkv proj -> Qh (scaled hi/lo), Kh (hi/lo), Vt (transposed bf16) ----------------
// Also initializes the static V^T rows (d=8 ones, d=9..15 zeros) for Vt0 AND Vt1.
__global__ __launch_bounds__(192) void qkv_proj_kernel(
    const float* __restrict__ X, const float* __restrict__ W,
    const float* __restrict__ bias,
    u16* __restrict__ Qh, u16* __restrict__ Kh, u16* __restrict__ Vt,
    u32* __restrict__ VtBoth)
{
    {
        const int gt = blockIdx.x * 192 + threadIdx.x;
        #pragma unroll
        for (int i = 0; i < 3; ++i) {
            const int idx = gt + i * 196608;
            if (idx < 524288) {
                const int region = idx >> 6, word = idx & 63;
                VtBoth[region * 128 + 64 + word] = (word < 8) ? 0x3f803f80u : 0u;
            }
        }
    }
    __shared__ __align__(16) float xsT[64 * 12];
    const int row0 = blockIdx.x * 8;
    const int t = threadIdx.x;
    if (t < 64) {
        #pragma unroll
        for (int r = 0; r < 8; ++r)
            xsT[t * 12 + r] = X[(size_t)(row0 + r) * 64 + t];
    }
    __syncthreads();
    const int j = t;
    const float bj = bias[j];
    float acc[8];
    #pragma unroll
    for (int r = 0; r < 8; ++r) acc[r] = bj;
    #pragma unroll 4
    for (int k = 0; k < 64; ++k) {
        const float w = W[k * 192 + j];
        const float4 x0 = *(const float4*)&xsT[k * 12];
        const float4 x1 = *(const float4*)&xsT[k * 12 + 4];
        acc[0] = fmaf(x0.x, w, acc[0]);
        acc[1] = fmaf(x0.y, w, acc[1]);
        acc[2] = fmaf(x0.z, w, acc[2]);
        acc[3] = fmaf(x0.w, w, acc[3]);
        acc[4] = fmaf(x1.x, w, acc[4]);
        acc[5] = fmaf(x1.y, w, acc[5]);
        acc[6] = fmaf(x1.z, w, acc[6]);
        acc[7] = fmaf(x1.w, w, acc[7]);
    }
    const int c = j & 63;
    const int h = c >> 3, d = c & 7;
    #pragma unroll
    for (int r = 0; r < 8; ++r) {
        const int R = row0 + r;
        const int bi = R >> 11, i = R & 2047;
        const int bh = bi * 8 + h;
        const float v = acc[r];
        if (j < 64) {
            const float qs = v * QK_SCALE;
            const u16 hh = f2bf(qs);
            const u16 ll = f2bf(qs - bf2f(hh));
            u16* qp = Qh + ((size_t)(bh * 2048 + i)) * 16 + d;
            qp[0] = hh; qp[8] = ll;
        } else if (j < 128) {
            const u16 hh = f2bf(v);
            const u16 ll = f2bf(v - bf2f(hh));
            u16* kp = Kh + ((size_t)(bh * 128 + (i >> 4)) * 16 + (i & 15)) * 16 + d;
            kp[0] = hh; kp[8] = ll;
        } else {
            Vt[((size_t)(bh * 128 + (i >> 4)) * 16 + d) * 16 + (i & 15)] = f2bf(v);
        }
    }
}

// ---------------- MFMA attention v9: 8 waves/SIMD occupancy experiment ----------------
// grid (bh=32, qt=64) = 2048 blocks = 8 blocks/CU = 32 waves/CU (needs VGPR<=64 ->
// launch_bounds(256,8); 2 q-chains per wave keeps per-wave state ~52 VGPR).
// Block: 32 q x 2048 keys. Wave w: keys [w*512,(w+1)*512), 32 segs, 2-seg prefetch.
// Math identical to R9: QK mfma_16x16x32 hi/lo, P=exp2->packtrunc, PV mfma16 + ones-row.
// No key-split: denominator broadcast via ds_bpermute, O normalized + written in-kernel.
__global__ __launch_bounds__(256, 8) void attn_mfma9_kernel(
    const u16* __restrict__ Qh, const u8* __restrict__ Khb,
    const u8* __restrict__ Vtb, float* __restrict__ M)
{
    __shared__ __align__(16) float Lr[4][2][64][4];   // [wave][qg][lane][4] = 8KB
    const int bh = blockIdx.x, qt = blockIdx.y;
    const int tid = threadIdx.x, w = tid >> 6, l = tid & 63;
    const int g = l >> 4, ql = l & 15;

    s8v bq[2];
    #pragma unroll
    for (int qg = 0; qg < 2; ++qg)
        bq[qg] = *(const s8v*)(Qh + ((size_t)(bh * 2048 + qt * 32 + qg * 16 + ql)) * 16
                               + (g >> 1) * 8);

    const size_t kvoff = (size_t)bh * 65536 + w * 16384;
    const u8* kptr = Khb + kvoff + ql * 32 + (g & 1) * 16;
    const u8* vptr = Vtb + kvoff + ql * 32 + g * 8;

    fx4 acc[2];
    acc[0] = fx4{0.f, 0.f, 0.f, 0.f};
    acc[1] = fx4{0.f, 0.f, 0.f, 0.f};
    const fx4 zf = {0.f, 0.f, 0.f, 0.f};

    s8v k0 = *(const s8v*)(kptr);
    s8v k1 = *(const s8v*)(kptr + 512);
    s4v v0 = *(const s4v*)(vptr);
    s4v v1 = *(const s4v*)(vptr + 512);

#define PROCESS(KA, VA)                                                         \
    {                                                                           \
        _Pragma("unroll")                                                       \
        for (int qg = 0; qg < 2; ++qg) {                                        \
            fx4 s = __builtin_amdgcn_mfma_f32_16x16x32_bf16(KA, bq[qg], zf, 0, 0, 0); \
            union { int i2[2]; s4v v; } bp;                                     \
            bp.i2[0] = packtrunc(EXP2(s[0]), EXP2(s[1]));                       \
            bp.i2[1] = packtrunc(EXP2(s[2]), EXP2(s[3]));                       \
            acc[qg] = mfma16(VA, bp.v, acc[qg]);                                \
        }                                                                       \
    }

    #pragma unroll 1
    for (int seg = 0; seg < 32; seg += 2) {
        const s8v k2 = *(const s8v*)(kptr + (seg + 2) * 512);
        const s4v v2 = *(const s4v*)(vptr + (seg + 2) * 512);
        const s8v k3 = *(const s8v*)(kptr + (seg + 3) * 512);
        const s4v v3 = *(const s4v*)(vptr + (seg + 3) * 512);
        PROCESS(k0, v0);
        PROCESS(k1, v1);
        k0 = k2; v0 = v2; k1 = k3; v1 = v3;
    }
#undef PROCESS

    // cross-wave reduction over key-quarters
    *(fx4*)&Lr[w][0][l][0] = acc[0];
    *(fx4*)&Lr[w][1][l][0] = acc[1];
    __syncthreads();

    if (w < 2) {                                   // wave w finalizes qg=w
        fx4 fin = {0.f, 0.f, 0.f, 0.f};
        #pragma unroll
        for (int wp = 0; wp < 4; ++wp) {
            const fx4 v = *(const fx4*)&Lr[wp][w][l][0];
            fin[0] += v[0]; fin[1] += v[1]; fin[2] += v[2]; fin[3] += v[3];
        }
        // denominator = O^T row 8 = lanes 32..47 (g==2, reg 0), col q
        const int lv_i = __builtin_amdgcn_ds_bpermute((32 + ql) * 4, __float_as_int(fin[0]));
        const float inv = 1.0f / __int_as_float(lv_i);
        if (g < 2) {
            const int qglob = qt * 32 + w * 16 + ql;
            const int b = bh >> 3, h = bh & 7;
            const float4 o = {fin[0] * inv, fin[1] * inv, fin[2] * inv, fin[3] * inv};
            *(float4*)(M + ((size_t)(b * 2048 + qglob)) * 64 + h * 8 + g * 4) = o;
        }
    }
}

// ---------------- proj64: mode 0 -> stage-2 Qh/Kh/Vt buffers; mode 1 -> plain f32 out ----------------
// q1 reshape: p-row rr, col c -> bh=bi*8+(rr>>8), key=(rr&255)*8+(c>>3), d=c&7
__global__ __launch_bounds__(64) void proj64_kernel(
    const float* __restrict__ X, const float* __restrict__ W,
    const float* __restrict__ bias,
    u16* __restrict__ Qh, u16* __restrict__ Kh, u16* __restrict__ Vt,
    float* __restrict__ Out, int mode)
{
    __shared__ __align__(16) float xsT[64 * 12];
    const int row0 = blockIdx.x * 8;
    const int c = threadIdx.x;
    #pragma unroll
    for (int r = 0; r < 8; ++r)
        xsT[c * 12 + r] = X[(size_t)(row0 + r) * 64 + c];
    __syncthreads();
    const float bc = bias[c];
    float acc[8];
    #pragma unroll
    for (int r = 0; r < 8; ++r) acc[r] = bc;
    #pragma unroll 4
    for (int k = 0; k < 64; ++k) {
        const float w = W[k * 64 + c];
        const float4 x0 = *(const float4*)&xsT[k * 12];
        const float4 x1 = *(const float4*)&xsT[k * 12 + 4];
        acc[0] = fmaf(x0.x, w, acc[0]);
        acc[1] = fmaf(x0.y, w, acc[1]);
        acc[2] = fmaf(x0.z, w, acc[2]);
        acc[3] = fmaf(x0.w, w, acc[3]);
        acc[4] = fmaf(x1.x, w, acc[4]);
        acc[5] = fmaf(x1.y, w, acc[5]);
        acc[6] = fmaf(x1.z, w, acc[6]);
        acc[7] = fmaf(x1.w, w, acc[7]);
    }
    if (mode == 0) {
        #pragma unroll
        for (int r = 0; r < 8; ++r) {
            const int R = row0 + r;
            const int bi = R >> 11, rr = R & 2047;
            const int bh = bi * 8 + (rr >> 8);
            const int key = (rr & 255) * 8 + (c >> 3);
            const int d = c & 7;
            const int kg = key >> 4, kr = key & 15;
            const float p = acc[r];
            const float qs = p * QK_SCALE;
            const u16 qh = f2bf(qs);
            const u16 qlo = f2bf(qs - bf2f(qh));
            const u16 kh = f2bf(p);
            const u16 kl = f2bf(p - bf2f(kh));
            u16* qp = Qh + ((size_t)(bh * 2048 + key)) * 16 + d;
            qp[0] = qh; qp[8] = qlo;
            u16* kp = Kh + ((size_t)(bh * 128 + kg) * 16 + kr) * 16 + d;
            kp[0] = kh; kp[8] = kl;
            Vt[((size_t)(bh * 128 + kg) * 16 + d) * 16 + kr] = f2bf(p);
        }
    } else {
        #pragma unroll
        for (int r = 0; r < 8; ++r)
            Out[(size_t)(row0 + r) * 64 + c] = acc[r];
    }
}

extern "C" void kernel_launch(void* const* d_in, const int* in_sizes, int n_in,
                              void* d_out, int out_size, void* d_ws, size_t ws_size,
                              hipStream_t stream) {
    const float* x    = (const float*)d_in[0];
    const float* Wqkv = (const float*)d_in[1];
    const float* bqkv = (const float*)d_in[2];
    const float* W1   = (const float*)d_in[3];
    const float* b1   = (const float*)d_in[4];
    float* out = (float*)d_out;
    u8* w8 = (u8*)d_ws;

    // byte layout (14 MiB used)
    u16*   Qh0  = (u16*)(w8);                       // 2 MiB
    u16*   Kh0  = (u16*)(w8 + (2u << 20));          // 2 MiB
    u16*   Vt0  = (u16*)(w8 + (4u << 20));          // 2 MiB
    u16*   Vt1  = (u16*)(w8 + (6u << 20));          // 2 MiB (adjacent to Vt0 for init)
    u16*   Qh1  = (u16*)(w8 + (8u << 20));          // 2 MiB
    u16*   Kh1  = (u16*)(w8 + (10u << 20));         // 2 MiB
    float* M1   = (float*)(w8 + (12u << 20));       // 2 MiB
    float* M2   = (float*)(w8);                     // overlays Qh0 (dead by then)

    qkv_proj_kernel<<<1024, 192, 0, stream>>>(x, Wqkv, bqkv, Qh0, Kh0, Vt0, (u32*)Vt0);
    attn_mfma9_kernel<<<dim3(32, 64), 256, 0, stream>>>(Qh0, (const u8*)Kh0, (const u8*)Vt0, M1);
    proj64_kernel<<<1024, 64, 0, stream>>>(M1, W1, b1, Qh1, Kh1, Vt1, nullptr, 0);
    attn_mfma9_kernel<<<dim3(32, 64), 256, 0, stream>>>(Qh1, (const u8*)Kh1, (const u8*)Vt1, M2);
    proj64_kernel<<<1024, 64, 0, stream>>>(M2, W1, b1, nullptr, nullptr, nullptr, out, 1);
}